// Round 10
// baseline (140.092 us; speedup 1.0000x reference)
//
#include <hip/hip_runtime.h>
#include <hip/hip_bf16.h>

#define N_NODES 50000
#define N_EDGES 500000
#define D 128
#define NUM_GRAPHS 512
#define BM 128
#define NB_NODES 196      // ceil(50000/256)
#define CVT_BLOCKS 6250   // 50000*128/(4*256)
#define OUT_BLOCKS 128    // 512*256 floats / (4*256)
#define WC_BLOCKS 16      // 128*256 bf16 / 256 threads / 8 elems

typedef __attribute__((ext_vector_type(8))) short bf16x8;
typedef __attribute__((ext_vector_type(4))) float f32x4;

static __device__ __forceinline__ unsigned short f2b(float f) {
  __hip_bfloat16 h = __float2bfloat16(f);
  return *reinterpret_cast<unsigned short*>(&h);
}
static __device__ __forceinline__ float blo(unsigned int p) {
  return __uint_as_float(p << 16);
}
static __device__ __forceinline__ float bhi(unsigned int p) {
  return __uint_as_float(p & 0xffff0000u);
}

// ---------------- fused prep: zero deg + zero out + cvt x + build swizzled weights ----------------

__global__ __launch_bounds__(256) void k_prep(
    const float* __restrict__ x, unsigned short* __restrict__ xb,
    int* __restrict__ deg, float* __restrict__ out,
    const float* __restrict__ Wl1, const float* __restrict__ Wr1,
    const float* __restrict__ Wl2, const float* __restrict__ Wr2,
    unsigned short* __restrict__ wc1, unsigned short* __restrict__ wc2) {
  int b = blockIdx.x;
  if (b < NB_NODES) {
    int i = b * 256 + threadIdx.x;
    if (i < N_NODES) deg[i] = 0;
  } else if (b < NB_NODES + CVT_BLOCKS) {
    int i = ((b - NB_NODES) * 256 + threadIdx.x) * 4;
    if (i < N_NODES * D) {
      float4 f = *(const float4*)&x[i];
      ushort4 o = make_ushort4(f2b(f.x), f2b(f.y), f2b(f.z), f2b(f.w));
      *(ushort4*)&xb[i] = o;
    }
  } else if (b < NB_NODES + CVT_BLOCKS + OUT_BLOCKS) {
    int i = ((b - NB_NODES - CVT_BLOCKS) * 256 + threadIdx.x) * 4;
    if (i < NUM_GRAPHS * 2 * D)
      *(float4*)&out[i] = make_float4(0.f, 0.f, 0.f, 0.f);
  } else {
    // combined [Wl|Wr] -> bf16, XOR-swizzled image: LDS-ready
    int b2 = b - NB_NODES - CVT_BLOCKS - OUT_BLOCKS;
    int layer = b2 >> 4;
    int idx = (b2 & 15) * 256 + threadIdx.x;   // 0..4095
    int j = idx >> 5;        // output row 0..127
    int kg = idx & 31;       // 8-elem k group, k0 = kg*8 in [0,256)
    int k0 = kg * 8;
    const float* wl = layer ? Wl2 : Wl1;
    const float* wr = layer ? Wr2 : Wr1;
    const float* srcp = (k0 < D) ? (wl + j * D + k0) : (wr + j * D + (k0 - D));
    float4 f0 = *(const float4*)srcp;
    float4 f1 = *(const float4*)(srcp + 4);
    bf16x8 wv;
    wv[0] = (short)f2b(f0.x); wv[1] = (short)f2b(f0.y);
    wv[2] = (short)f2b(f0.z); wv[3] = (short)f2b(f0.w);
    wv[4] = (short)f2b(f1.x); wv[5] = (short)f2b(f1.y);
    wv[6] = (short)f2b(f1.z); wv[7] = (short)f2b(f1.w);
    unsigned short* wc = layer ? wc2 : wc1;
    int byteofs = j * 512 + ((kg * 16) ^ ((j & 7) << 4));
    *(bf16x8*)((char*)wc + byteofs) = wv;
  }
}

// ---------------- CSR build ----------------

__global__ void k_count(const int* __restrict__ dst, int* __restrict__ deg) {
  int e = blockIdx.x * 256 + threadIdx.x;
  if (e < N_EDGES) atomicAdd(&deg[dst[e]], 1);
}

__global__ void k_scan1(const int* __restrict__ deg, int* __restrict__ bsum) {
  __shared__ int s[256];
  int t = threadIdx.x;
  int i = blockIdx.x * 256 + t;
  s[t] = (i < N_NODES) ? deg[i] : 0;
  __syncthreads();
  for (int off = 128; off > 0; off >>= 1) {
    if (t < off) s[t] += s[t + off];
    __syncthreads();
  }
  if (t == 0) bsum[blockIdx.x] = s[0];
}

__global__ void k_scan2(int* __restrict__ bsum, int nb) {
  __shared__ int s[256];
  int t = threadIdx.x;
  int v = (t < nb) ? bsum[t] : 0;
  s[t] = v;
  __syncthreads();
  for (int off = 1; off < 256; off <<= 1) {
    int add = (t >= off) ? s[t - off] : 0;
    __syncthreads();
    s[t] += add;
    __syncthreads();
  }
  if (t < nb) bsum[t] = s[t] - v;  // exclusive
}

__global__ void k_scan3(const int* __restrict__ deg, const int* __restrict__ bsum,
                        int* __restrict__ rowptr, int* __restrict__ pos) {
  __shared__ int s[256];
  int t = threadIdx.x;
  int i = blockIdx.x * 256 + t;
  int v = (i < N_NODES) ? deg[i] : 0;
  s[t] = v;
  __syncthreads();
  for (int off = 1; off < 256; off <<= 1) {
    int add = (t >= off) ? s[t - off] : 0;
    __syncthreads();
    s[t] += add;
    __syncthreads();
  }
  int excl = s[t] - v + bsum[blockIdx.x];
  if (i < N_NODES) { rowptr[i] = excl; pos[i] = excl; }
  if (i == N_NODES - 1) rowptr[N_NODES] = excl + v;
}

__global__ void k_bucket(const int* __restrict__ src, const int* __restrict__ dst,
                         int* __restrict__ pos, int* __restrict__ esrc) {
  int e = blockIdx.x * 256 + threadIdx.x;
  if (e < N_EDGES) {
    int slot = atomicAdd(&pos[dst[e]], 1);
    esrc[slot] = src[e];
  }
}

// ---------------- mean aggregation: one wave per TWO nodes, 16 lanes x 16B per edge ----------------
// Merged main loop keeps 4 independent uint4 gathers in flight (2 per node).
// Exact per-lane bounds everywhere: every edge row loaded exactly once.

__global__ __launch_bounds__(256) void k_agg(
    const unsigned short* __restrict__ xb, const int* __restrict__ rowptr,
    const int* __restrict__ esrc, unsigned short* __restrict__ aggb) {
  int wid = (blockIdx.x * 256 + threadIdx.x) >> 6;
  int lane = threadIdx.x & 63;
  const int q = lane >> 4;      // edge sub-slot 0..3
  const int c = lane & 15;      // col group: cols c*8..c*8+7
  int n0 = wid * 2, n1 = n0 + 1;
  if (n0 >= N_NODES) return;
  int beg0 = rowptr[n0], end0 = rowptr[n0 + 1];
  int beg1 = 0, end1 = 0;
  if (n1 < N_NODES) { beg1 = rowptr[n1]; end1 = rowptr[n1 + 1]; }

  float a0[8], a1[8];
#pragma unroll
  for (int i = 0; i < 8; ++i) { a0[i] = 0.f; a1[i] = 0.f; }

  int e0 = beg0 + q, e1 = beg1 + q;
  // merged main loop: 4 loads in flight while both nodes have full pairs
  while (e0 + 4 < end0 && e1 + 4 < end1) {
    int s00 = esrc[e0], s01 = esrc[e0 + 4];
    int s10 = esrc[e1], s11 = esrc[e1 + 4];
    uint4 p00 = *(const uint4*)&xb[(size_t)s00 * D + c * 8];
    uint4 p01 = *(const uint4*)&xb[(size_t)s01 * D + c * 8];
    uint4 p10 = *(const uint4*)&xb[(size_t)s10 * D + c * 8];
    uint4 p11 = *(const uint4*)&xb[(size_t)s11 * D + c * 8];
    a0[0] += blo(p00.x) + blo(p01.x); a0[1] += bhi(p00.x) + bhi(p01.x);
    a0[2] += blo(p00.y) + blo(p01.y); a0[3] += bhi(p00.y) + bhi(p01.y);
    a0[4] += blo(p00.z) + blo(p01.z); a0[5] += bhi(p00.z) + bhi(p01.z);
    a0[6] += blo(p00.w) + blo(p01.w); a0[7] += bhi(p00.w) + bhi(p01.w);
    a1[0] += blo(p10.x) + blo(p11.x); a1[1] += bhi(p10.x) + bhi(p11.x);
    a1[2] += blo(p10.y) + blo(p11.y); a1[3] += bhi(p10.y) + bhi(p11.y);
    a1[4] += blo(p10.z) + blo(p11.z); a1[5] += bhi(p10.z) + bhi(p11.z);
    a1[6] += blo(p10.w) + blo(p11.w); a1[7] += bhi(p10.w) + bhi(p11.w);
    e0 += 8; e1 += 8;
  }
  // finish node 0
  for (; e0 + 4 < end0; e0 += 8) {
    int s00 = esrc[e0], s01 = esrc[e0 + 4];
    uint4 p00 = *(const uint4*)&xb[(size_t)s00 * D + c * 8];
    uint4 p01 = *(const uint4*)&xb[(size_t)s01 * D + c * 8];
    a0[0] += blo(p00.x) + blo(p01.x); a0[1] += bhi(p00.x) + bhi(p01.x);
    a0[2] += blo(p00.y) + blo(p01.y); a0[3] += bhi(p00.y) + bhi(p01.y);
    a0[4] += blo(p00.z) + blo(p01.z); a0[5] += bhi(p00.z) + bhi(p01.z);
    a0[6] += blo(p00.w) + blo(p01.w); a0[7] += bhi(p00.w) + bhi(p01.w);
  }
  if (e0 < end0) {
    int s00 = esrc[e0];
    uint4 p = *(const uint4*)&xb[(size_t)s00 * D + c * 8];
    a0[0] += blo(p.x); a0[1] += bhi(p.x);
    a0[2] += blo(p.y); a0[3] += bhi(p.y);
    a0[4] += blo(p.z); a0[5] += bhi(p.z);
    a0[6] += blo(p.w); a0[7] += bhi(p.w);
  }
  // finish node 1
  for (; e1 + 4 < end1; e1 += 8) {
    int s10 = esrc[e1], s11 = esrc[e1 + 4];
    uint4 p10 = *(const uint4*)&xb[(size_t)s10 * D + c * 8];
    uint4 p11 = *(const uint4*)&xb[(size_t)s11 * D + c * 8];
    a1[0] += blo(p10.x) + blo(p11.x); a1[1] += bhi(p10.x) + bhi(p11.x);
    a1[2] += blo(p10.y) + blo(p11.y); a1[3] += bhi(p10.y) + bhi(p11.y);
    a1[4] += blo(p10.z) + blo(p11.z); a1[5] += bhi(p10.z) + bhi(p11.z);
    a1[6] += blo(p10.w) + blo(p11.w); a1[7] += bhi(p10.w) + bhi(p11.w);
  }
  if (e1 < end1) {
    int s10 = esrc[e1];
    uint4 p = *(const uint4*)&xb[(size_t)s10 * D + c * 8];
    a1[0] += blo(p.x); a1[1] += bhi(p.x);
    a1[2] += blo(p.y); a1[3] += bhi(p.y);
    a1[4] += blo(p.z); a1[5] += bhi(p.z);
    a1[6] += blo(p.w); a1[7] += bhi(p.w);
  }

  // reduce across the 4 edge sub-slots
#pragma unroll
  for (int i = 0; i < 8; ++i) {
    a0[i] += __shfl_xor(a0[i], 16);
    a0[i] += __shfl_xor(a0[i], 32);
    a1[i] += __shfl_xor(a1[i], 16);
    a1[i] += __shfl_xor(a1[i], 32);
  }

  if (q == 0) {
    float inv = 1.f / fmaxf((float)(end0 - beg0), 1.f);
    uint4 o;
    o.x = (unsigned int)f2b(a0[0] * inv) | ((unsigned int)f2b(a0[1] * inv) << 16);
    o.y = (unsigned int)f2b(a0[2] * inv) | ((unsigned int)f2b(a0[3] * inv) << 16);
    o.z = (unsigned int)f2b(a0[4] * inv) | ((unsigned int)f2b(a0[5] * inv) << 16);
    o.w = (unsigned int)f2b(a0[6] * inv) | ((unsigned int)f2b(a0[7] * inv) << 16);
    *(uint4*)&aggb[(size_t)n0 * D + c * 8] = o;
  } else if (q == 1 && n1 < N_NODES) {
    float inv = 1.f / fmaxf((float)(end1 - beg1), 1.f);
    uint4 o;
    o.x = (unsigned int)f2b(a1[0] * inv) | ((unsigned int)f2b(a1[1] * inv) << 16);
    o.y = (unsigned int)f2b(a1[2] * inv) | ((unsigned int)f2b(a1[3] * inv) << 16);
    o.z = (unsigned int)f2b(a1[4] * inv) | ((unsigned int)f2b(a1[5] * inv) << 16);
    o.w = (unsigned int)f2b(a1[6] * inv) | ((unsigned int)f2b(a1[7] * inv) << 16);
    *(uint4*)&aggb[(size_t)n1 * D + c * 8] = o;
  }
}

// ---------------- MFMA GEMM: relu([Ab|Xb] @ Wc^T), fused segmented max-pool ----------------
// Wc is the pre-swizzled bf16 LDS image built by k_prep. Yb may be nullptr.

__global__ __launch_bounds__(512) void k_gemm(
    const unsigned short* __restrict__ Ab, const unsigned short* __restrict__ Xb,
    const unsigned short* __restrict__ Wc,
    unsigned short* __restrict__ Yb, const int* __restrict__ batch,
    unsigned int* __restrict__ pool, int col_ofs) {
  __shared__ unsigned short Wlds[32768 + 256];  // 64KB weights/tile + 512B batch ids
  const int tid = threadIdx.x;
  const int w = tid >> 6, lane = tid & 63;
  const int lr = lane & 15, lh = lane >> 4;
  const int row0 = blockIdx.x * BM;
  const int row = row0 + w * 16 + lr;

  // stage pre-swizzled weights: linear 64KB copy, fully coalesced
#pragma unroll
  for (int i = 0; i < 8; ++i) {
    int ofs = i * 8192 + tid * 16;
    *(bf16x8*)((char*)Wlds + ofs) = *(const bf16x8*)((const char*)Wc + ofs);
  }

  // A fragments: row `row`, k in [0,256): first half Ab, second half Xb
  bf16x8 a[8];
  if (row < N_NODES) {
    const unsigned short* ar = Ab + (size_t)row * D;
    const unsigned short* xr = Xb + (size_t)row * D;
#pragma unroll
    for (int kk = 0; kk < 4; ++kk)
      a[kk] = *(const bf16x8*)(ar + kk * 32 + lh * 8);
#pragma unroll
    for (int kk = 0; kk < 4; ++kk)
      a[4 + kk] = *(const bf16x8*)(xr + kk * 32 + lh * 8);
  } else {
#pragma unroll
    for (int kk = 0; kk < 8; ++kk)
      a[kk] = (bf16x8){0, 0, 0, 0, 0, 0, 0, 0};
  }
  __syncthreads();

  f32x4 acc[8];
#pragma unroll
  for (int jt = 0; jt < 8; ++jt) acc[jt] = (f32x4){0.f, 0.f, 0.f, 0.f};

#pragma unroll
  for (int jt = 0; jt < 8; ++jt) {
    int jj = jt * 16 + lr;
    const char* wbase = (const char*)Wlds + jj * 512;
    int sw = (jj & 7) << 4;
#pragma unroll
    for (int kk = 0; kk < 8; ++kk) {
      bf16x8 b = *(const bf16x8*)(wbase + ((kk * 64 + lh * 16) ^ sw));
      acc[jt] = __builtin_amdgcn_mfma_f32_16x16x32_bf16(a[kk], b, acc[jt], 0, 0, 0);
    }
  }

  __syncthreads();  // all waves done reading weights; reuse LDS for output tile
  // write relu(acc) as bf16 tile [128 rows][128 cols], swizzled
#pragma unroll
  for (int jt = 0; jt < 8; ++jt) {
#pragma unroll
    for (int r = 0; r < 4; ++r) {
      int rl = w * 16 + lh * 4 + r;
      int col = jt * 16 + lr;
      float v = acc[jt][r];
      v = v > 0.f ? v : 0.f;
      int byteofs = rl * 256 + ((col * 2) ^ ((rl & 7) << 4));
      *(unsigned short*)((char*)Wlds + byteofs) = f2b(v);
    }
  }
  // batch ids for this block's rows (separate LDS region)
  int* sb = (int*)(Wlds + 32768);
  if (tid < BM) {
    int grow = row0 + tid;
    sb[tid] = (grow < N_NODES) ? batch[grow] : -1;
  }
  __syncthreads();

  // coalesced bf16x8 stores (layer 1 only)
  if (Yb != nullptr) {
    int rl = tid >> 2, c0 = (tid & 3) * 64;  // c0 in bytes
    int grow = row0 + rl;
    if (grow < N_NODES) {
#pragma unroll
      for (int cc = 0; cc < 4; ++cc) {
        int byteofs = rl * 256 + ((c0 + cc * 16) ^ ((rl & 7) << 4));
        bf16x8 v = *(const bf16x8*)((char*)Wlds + byteofs);
        *(bf16x8*)&Yb[(size_t)grow * D + (c0 + cc * 16) / 2] = v;
      }
    }
  }

  // segmented max-pool: all 512 threads, 32-row chunks
  // rows sorted by graph; ushort compare == float compare (relu >= 0)
  {
    int col = tid & 127;
    int r0 = (tid >> 7) * 32;
    unsigned short run = 0;
    int curg = sb[r0];
    for (int r = r0; r < r0 + 32; ++r) {
      int g = sb[r];
      if (g != curg) {
        if (curg >= 0 && run)
          atomicMax(&pool[curg * (2 * D) + col_ofs + col], ((unsigned int)run) << 16);
        curg = g;
        run = 0;
      }
      int byteofs = r * 256 + ((col * 2) ^ ((r & 7) << 4));
      unsigned short v = *(const unsigned short*)((char*)Wlds + byteofs);
      run = run > v ? run : v;
    }
    if (curg >= 0 && run)
      atomicMax(&pool[curg * (2 * D) + col_ofs + col], ((unsigned int)run) << 16);
  }
}

// ---------------- launch ----------------

extern "C" void kernel_launch(void* const* d_in, const int* in_sizes, int n_in,
                              void* d_out, int out_size, void* d_ws, size_t ws_size,
                              hipStream_t stream) {
  const float* x = (const float*)d_in[0];
  const int* ei = (const int*)d_in[1];
  const int* src = ei;               // edge_index[0]
  const int* dst = ei + N_EDGES;     // edge_index[1]
  const int* batch = (const int*)d_in[2];
  const float* Wl1 = (const float*)d_in[3];
  const float* Wr1 = (const float*)d_in[4];
  const float* Wl2 = (const float*)d_in[5];
  const float* Wr2 = (const float*)d_in[6];

  char* ws = (char*)d_ws;
  size_t off = 0;
  auto alloc = [&](size_t bytes) -> void* {
    void* p = ws + off;
    off += (bytes + 511) & ~(size_t)511;
    return p;
  };
  int* deg = (int*)alloc((size_t)N_NODES * 4);
  int* rowptr = (int*)alloc((size_t)(N_NODES + 1) * 4);
  int* pos = (int*)alloc((size_t)N_NODES * 4);
  int* bsum = (int*)alloc(256 * 4);
  int* esrc = (int*)alloc((size_t)N_EDGES * 4);
  unsigned short* xb = (unsigned short*)alloc((size_t)N_NODES * D * 2);
  unsigned short* aggb = (unsigned short*)alloc((size_t)N_NODES * D * 2);
  unsigned short* x1b = (unsigned short*)alloc((size_t)N_NODES * D * 2);
  unsigned short* wc1 = (unsigned short*)alloc(65536);
  unsigned short* wc2 = (unsigned short*)alloc(65536);
  (void)ws_size; (void)in_sizes; (void)n_in; (void)out_size;

  // prep: zero deg + cvt x + zero out + build swizzled weight images
  k_prep<<<NB_NODES + CVT_BLOCKS + OUT_BLOCKS + 2 * WC_BLOCKS, 256, 0, stream>>>(
      x, xb, deg, (float*)d_out, Wl1, Wr1, Wl2, Wr2, wc1, wc2);

  k_count<<<(N_EDGES + 255) / 256, 256, 0, stream>>>(dst, deg);
  k_scan1<<<NB_NODES, 256, 0, stream>>>(deg, bsum);
  k_scan2<<<1, 256, 0, stream>>>(bsum, NB_NODES);
  k_scan3<<<NB_NODES, 256, 0, stream>>>(deg, bsum, rowptr, pos);
  k_bucket<<<(N_EDGES + 255) / 256, 256, 0, stream>>>(src, dst, pos, esrc);

  int agg_blocks = 6250;  // 25000 waves, 2 nodes each
  int gemm_blocks = (N_NODES + BM - 1) / BM;  // 391

  // layer 1: pool x1 into cols [0,128)
  k_agg<<<agg_blocks, 256, 0, stream>>>(xb, rowptr, esrc, aggb);
  k_gemm<<<gemm_blocks, 512, 0, stream>>>(aggb, xb, wc1, x1b, batch,
                                          (unsigned int*)d_out, 0);
  // layer 2: x2 never materialized; pool into cols [128,256)
  k_agg<<<agg_blocks, 256, 0, stream>>>(x1b, rowptr, esrc, aggb);
  k_gemm<<<gemm_blocks, 512, 0, stream>>>(aggb, x1b, wc2, nullptr, batch,
                                          (unsigned int*)d_out, D);
}